// Round 9
// baseline (1954.300 us; speedup 1.0000x reference)
//
#include <hip/hip_runtime.h>
#include <hip/hip_bf16.h>
#include <cstdint>

// Problem dims
#define T_STEPS 128
#define BATCH   32
#define VOCAB   50000
#define EDIM    512
#define HDIM    512
#define GDIM    2048          // 4*H
#define MROWS   4096          // T*B
#define VPAD    50048         // padded rows of decWb
#define BH      (BATCH * HDIM)
#define NTILE_N 782           // decode n-tiles (64 cols each) covering 50048
#define NTILES_TOT (32 * NTILE_N)   // 25024 decode tiles (128x64)
#define FUSED_TILES 24046     // tiles carried inside the recurrence (rest: tail)

typedef short bf16x8 __attribute__((ext_vector_type(8)));
typedef float f32x4  __attribute__((ext_vector_type(4)));
typedef unsigned short us4 __attribute__((ext_vector_type(4)));
typedef unsigned short us8 __attribute__((ext_vector_type(8)));

#define MFMA16(a, b, c) __builtin_amdgcn_mfma_f32_16x16x32_bf16(a, b, c, 0, 0, 0)

__device__ __forceinline__ float fsigmoid(float x) { return 1.0f / (1.0f + __expf(-x)); }
__device__ __forceinline__ float ftanh(float x)    { return 1.0f - 2.0f / (1.0f + __expf(2.0f * x)); }

// round-to-nearest-even fp32 -> bf16 bits
__device__ __forceinline__ unsigned short f2bf(float f) {
    unsigned int u = __float_as_uint(f);
    u = (u + 0x7fffu + ((u >> 16) & 1u)) >> 16;
    return (unsigned short)u;
}

// ---------------------------------------------------------------------------
// Prologue kernels
// ---------------------------------------------------------------------------

// Gate-interleaved pack+convert for all 4 recurrent weight mats in one launch
__global__ __launch_bounds__(64) void pack_all(const float* __restrict__ s0,
                                               const float* __restrict__ s1,
                                               const float* __restrict__ s2,
                                               const float* __restrict__ s3,
                                               unsigned short* __restrict__ d0,
                                               unsigned short* __restrict__ d1,
                                               unsigned short* __restrict__ d2,
                                               unsigned short* __restrict__ d3) {
    const int which = blockIdx.x >> 11;             // 0..3
    const int n = blockIdx.x & 2047;                // packed row
    const float* src = (which == 0) ? s0 : (which == 1) ? s1 : (which == 2) ? s2 : s3;
    unsigned short* dst = (which == 0) ? d0 : (which == 1) ? d1 : (which == 2) ? d2 : d3;
    const int orig = (n & 3) * 512 + (n >> 2);
    const int k = threadIdx.x * 8;
    const float* s = src + (long)orig * 512 + k;
    float4 a = *(const float4*)s;
    float4 b = *(const float4*)(s + 4);
    us8 v;
    v[0] = f2bf(a.x); v[1] = f2bf(a.y); v[2] = f2bf(a.z); v[3] = f2bf(a.w);
    v[4] = f2bf(b.x); v[5] = f2bf(b.y); v[6] = f2bf(b.z); v[7] = f2bf(b.w);
    *(us8*)(dst + (long)n * 512 + k) = v;
}

// packed bias sums
__global__ __launch_bounds__(256) void pack_bias(const float* __restrict__ bih0,
                                                 const float* __restrict__ bhh0,
                                                 const float* __restrict__ bih1,
                                                 const float* __restrict__ bhh1,
                                                 float* __restrict__ b0p,
                                                 float* __restrict__ b1p) {
    const int n = blockIdx.x * 256 + threadIdx.x;   // 0..2047
    const int orig = (n & 3) * 512 + (n >> 2);
    b0p[n] = bih0[orig] + bhh0[orig];
    b1p[n] = bih1[orig] + bhh1[orig];
}

// X[r, :] = bf16(emb[seq[r], :])
__global__ __launch_bounds__(256) void gather_x(const int* __restrict__ seq,
                                                const float* __restrict__ emb,
                                                unsigned short* __restrict__ Xbf) {
    long i = ((long)blockIdx.x * 256 + threadIdx.x) * 4;
    if (i >= (long)MROWS * EDIM) return;
    int r   = (int)(i >> 9);
    int col = (int)(i & 511);
    const float* er = emb + (long)seq[r] * EDIM + col;
    float4 e = *(const float4*)er;
    us4 v;
    v[0] = f2bf(e.x); v[1] = f2bf(e.y); v[2] = f2bf(e.z); v[3] = f2bf(e.w);
    *(us4*)(Xbf + i) = v;
}

// c0 init for both layers; h0 = 0 in slot 0 of y buffers
__global__ __launch_bounds__(256) void init_c0(const int* __restrict__ word,
                                               const float* __restrict__ emb,
                                               const float* __restrict__ w2hW,
                                               const float* __restrict__ w2hb,
                                               float* __restrict__ c0s, float* __restrict__ c1s,
                                               unsigned short* __restrict__ y0bf,
                                               unsigned short* __restrict__ y1bf) {
    const int idx = blockIdx.x * 256 + threadIdx.x;   // 0..16383
    const int b = idx >> 9, hh = idx & 511;
    const float* er = emb + (long)word[b] * EDIM;
    const float* wr = w2hW + (long)hh * EDIM;
    float acc = w2hb[hh];
    #pragma unroll 4
    for (int k = 0; k < EDIM; k += 4) {
        float4 e4 = *(const float4*)(er + k);
        float4 w4 = *(const float4*)(wr + k);
        acc += e4.x * w4.x + e4.y * w4.y + e4.z * w4.z + e4.w * w4.w;
    }
    c0s[idx] = acc;
    c1s[idx] = acc;
    y0bf[idx] = 0;
    y1bf[idx] = 0;
}

// ---------------------------------------------------------------------------
// MFMA GEMM (used for G0): C = A@Bt^T + bias, n-fastest order, LDS-staged
// epilogue. Blocks >= ngemm carry dec_W fp32->bf16 conversion slices
// (independent work overlapped on otherwise-idle CUs).
// ---------------------------------------------------------------------------
__global__ __launch_bounds__(256) void gemm_bt128(const unsigned short* __restrict__ A,
                                                  const unsigned short* __restrict__ Bt,
                                                  float* __restrict__ C,
                                                  const float* __restrict__ bias1,
                                                  int K, int Nreal, long ldc, int ntn,
                                                  const float* __restrict__ cvsrc,
                                                  unsigned short* __restrict__ cvdst,
                                                  int ngemm) {
    const int tid  = threadIdx.x;
    if (blockIdx.x >= ngemm) {
        // dec_W conversion slice: 2048 elems/block
        long i = ((long)(blockIdx.x - ngemm) * 256 + tid) * 8;
        if (i >= (long)VPAD * EDIM) return;
        long row = i >> 9;
        us8 v;
        if (row < VOCAB) {
            float4 a = *(const float4*)(cvsrc + i);
            float4 b = *(const float4*)(cvsrc + i + 4);
            v[0] = f2bf(a.x); v[1] = f2bf(a.y); v[2] = f2bf(a.z); v[3] = f2bf(a.w);
            v[4] = f2bf(b.x); v[5] = f2bf(b.y); v[6] = f2bf(b.z); v[7] = f2bf(b.w);
        } else {
            v = (us8)0;
        }
        *(us8*)(cvdst + i) = v;
        return;
    }

    __shared__ __align__(16) unsigned char smem[34048];   // As|Bs / ctile
    unsigned short* As = (unsigned short*)smem;
    unsigned short* Bs = (unsigned short*)(smem + 16384);
    float* ctile = (float*)smem;                          // [64][132]

    const long m0  = (long)(blockIdx.x / ntn) * 128;
    const long n0  = (long)(blockIdx.x % ntn) * 128;
    const int lane = tid & 63;
    const int wave = tid >> 6;
    const int wr = wave >> 1, wc = wave & 1;
    const int fr = lane & 15, fq = lane >> 4;

    f32x4 acc[4][4];
    #pragma unroll
    for (int i = 0; i < 4; ++i)
        #pragma unroll
        for (int j = 0; j < 4; ++j) acc[i][j] = (f32x4)0.0f;

    const int srow = tid >> 3;
    const int scol = (tid & 7) * 8;

    for (int kt = 0; kt < K; kt += 64) {
        #pragma unroll
        for (int i = 0; i < 4; ++i) {
            const unsigned short* ga = A  + (m0 + i * 32 + srow) * K + kt + scol;
            const unsigned short* gb = Bt + (n0 + i * 32 + srow) * K + kt + scol;
            __builtin_amdgcn_global_load_lds((const __attribute__((address_space(1))) void*)ga,
                                             (__attribute__((address_space(3))) void*)(As + i * 2048 + tid * 8),
                                             16, 0, 0);
            __builtin_amdgcn_global_load_lds((const __attribute__((address_space(1))) void*)gb,
                                             (__attribute__((address_space(3))) void*)(Bs + i * 2048 + tid * 8),
                                             16, 0, 0);
        }
        asm volatile("s_waitcnt vmcnt(0)" ::: "memory");
        __syncthreads();
        #pragma unroll
        for (int ks = 0; ks < 64; ks += 32) {
            bf16x8 af[4], bfr[4];
            #pragma unroll
            for (int mi = 0; mi < 4; ++mi)
                af[mi] = *(const bf16x8*)&As[(wr * 64 + mi * 16 + fr) * 64 + ks + fq * 8];
            #pragma unroll
            for (int ni = 0; ni < 4; ++ni)
                bfr[ni] = *(const bf16x8*)&Bs[(wc * 64 + ni * 16 + fr) * 64 + ks + fq * 8];
            #pragma unroll
            for (int mi = 0; mi < 4; ++mi)
                #pragma unroll
                for (int ni = 0; ni < 4; ++ni)
                    acc[mi][ni] = MFMA16(af[mi], bfr[ni], acc[mi][ni]);
        }
        __syncthreads();
    }

    #pragma unroll
    for (int h = 0; h < 2; ++h) {
        if (wr == h) {
            #pragma unroll
            for (int ni = 0; ni < 4; ++ni) {
                const long col = n0 + wc * 64 + ni * 16 + fr;
                float bs = (col < Nreal && bias1) ? bias1[col] : 0.0f;
                #pragma unroll
                for (int mi = 0; mi < 4; ++mi)
                    #pragma unroll
                    for (int r = 0; r < 4; ++r)
                        ctile[(mi * 16 + fq * 4 + r) * 132 + wc * 64 + ni * 16 + fr] =
                            acc[mi][ni][r] + bs;
            }
        }
        __syncthreads();
        #pragma unroll
        for (int j = 0; j < 8; ++j) {
            const int flat = tid + j * 256;
            const int row = flat >> 5, colq = flat & 31;
            const long col4 = n0 + colq * 4;
            if (col4 < Nreal) {
                f32x4 v = *(const f32x4*)&ctile[row * 132 + colq * 4];
                *(f32x4*)&C[(m0 + h * 64 + row) * ldc + col4] = v;
            }
        }
        __syncthreads();
    }
}

// ---------------------------------------------------------------------------
// Decode tile (128 rows x 64 cols of decoded = y1 @ dec_W^T + dec_b), K=512.
// 512 threads = 8 waves (4x2), each wave 32x32 via 2x2 16x16x32 frags.
// LDS: As 16KB | Bs 8KB; epilogue ctile [64][68] aliases the same memory.
// ---------------------------------------------------------------------------
__device__ __forceinline__ void decode_tile(int tau,
                                            const unsigned short* __restrict__ y1A,
                                            const unsigned short* __restrict__ decWb,
                                            const float* __restrict__ dec_b,
                                            float* __restrict__ out,
                                            char* smem, int tid) {
    unsigned short* As = (unsigned short*)smem;            // [128][64]
    unsigned short* Bs = (unsigned short*)(smem + 16384);  // [64][64]
    float* ctile = (float*)smem;                           // [64][68]

    const int mi = tau / NTILE_N, nj = tau % NTILE_N;
    const long m0 = (long)mi * 128, n0 = (long)nj * 64;
    const int srow = tid >> 3, scol = (tid & 7) * 8;
    const int wv = tid >> 6, lane = tid & 63;
    const int wr = wv >> 1, wc = wv & 1;
    const int fr = lane & 15, fq = lane >> 4;

    f32x4 acc[2][2];
    acc[0][0] = (f32x4)0.0f; acc[0][1] = (f32x4)0.0f;
    acc[1][0] = (f32x4)0.0f; acc[1][1] = (f32x4)0.0f;

    for (int kt = 0; kt < 512; kt += 64) {
        #pragma unroll
        for (int i = 0; i < 2; ++i) {
            const unsigned short* ga = y1A + (m0 + i * 64 + srow) * 512 + kt + scol;
            __builtin_amdgcn_global_load_lds((const __attribute__((address_space(1))) void*)ga,
                                             (__attribute__((address_space(3))) void*)(As + i * 4096 + tid * 8),
                                             16, 0, 0);
        }
        const unsigned short* gb = decWb + (n0 + srow) * 512 + kt + scol;
        __builtin_amdgcn_global_load_lds((const __attribute__((address_space(1))) void*)gb,
                                         (__attribute__((address_space(3))) void*)(Bs + tid * 8),
                                         16, 0, 0);
        asm volatile("s_waitcnt vmcnt(0)" ::: "memory");
        __syncthreads();
        #pragma unroll
        for (int ks = 0; ks < 64; ks += 32) {
            bf16x8 af[2], bfr[2];
            #pragma unroll
            for (int m2 = 0; m2 < 2; ++m2)
                af[m2] = *(const bf16x8*)&As[(wr * 32 + m2 * 16 + fr) * 64 + ks + fq * 8];
            #pragma unroll
            for (int n2 = 0; n2 < 2; ++n2)
                bfr[n2] = *(const bf16x8*)&Bs[(wc * 32 + n2 * 16 + fr) * 64 + ks + fq * 8];
            #pragma unroll
            for (int m2 = 0; m2 < 2; ++m2)
                #pragma unroll
                for (int n2 = 0; n2 < 2; ++n2)
                    acc[m2][n2] = MFMA16(af[m2], bfr[n2], acc[m2][n2]);
        }
        __syncthreads();
    }

    // epilogue: two 64-row halves through LDS, contiguous 256B row segments
    #pragma unroll
    for (int h = 0; h < 2; ++h) {
        if ((wr >> 1) == h) {
            #pragma unroll
            for (int n2 = 0; n2 < 2; ++n2) {
                const long col = n0 + wc * 32 + n2 * 16 + fr;
                float bs = (col < VOCAB) ? dec_b[col] : 0.0f;
                #pragma unroll
                for (int m2 = 0; m2 < 2; ++m2)
                    #pragma unroll
                    for (int r = 0; r < 4; ++r)
                        ctile[((wr & 1) * 32 + m2 * 16 + fq * 4 + r) * 68 + wc * 32 + n2 * 16 + fr] =
                            acc[m2][n2][r] + bs;
            }
        }
        __syncthreads();
        #pragma unroll
        for (int j = 0; j < 2; ++j) {
            const int flat = tid + j * 512;          // 0..1023 float4 units
            const int row = flat >> 4, colq = flat & 15;
            const long col4 = n0 + colq * 4;
            if (col4 < VOCAB) {
                f32x4 v = *(const f32x4*)&ctile[row * 68 + colq * 4];
                *(f32x4*)&out[(m0 + h * 64 + row) * (long)VOCAB + col4] = v;
            }
        }
        __syncthreads();
    }
}

// ---------------------------------------------------------------------------
// LSTM step (skewed) + fused decode tiles. Blocks 0..63 layer0 step t,
// 64..127 layer1 step t-1; blocks 128.. carry decode tiles [sd, sd+ntiles)
// whose y1 rows were finalized in earlier dispatches (schedule proven behind
// the readiness frontier host-side). Idle-CU work: decode rides free under
// the recurrence's 6us critical path.
// ---------------------------------------------------------------------------
__global__ __launch_bounds__(512) void lstm_step2(
        const float* __restrict__ G0,
        const unsigned short* __restrict__ Whh0p,
        const unsigned short* __restrict__ Wih1p,
        const unsigned short* __restrict__ Whh1p,
        const float* __restrict__ b1p,
        unsigned short* __restrict__ y0bf,         // [T+1][32][512] (slot0 = h init)
        unsigned short* __restrict__ y1bf,
        float* __restrict__ c0s, float* __restrict__ c1s,
        float* __restrict__ hf,
        const unsigned short* __restrict__ decWb,
        const float* __restrict__ dec_b,
        float* __restrict__ out,
        int t, int sd) {
    __shared__ __align__(16) char smem[32768];
    int bid = blockIdx.x;
    const int tid  = threadIdx.x;

    if (bid >= 128) {
        decode_tile(sd + bid - 128, y1bf + BH, decWb, dec_b, out, smem, tid);
        return;
    }

    float (*part)[32][32] = (float(*)[32][32])smem;
    const int wv   = tid >> 6, lane = tid & 63;
    const int fr   = lane & 15, fq = lane >> 4;

    int layer, tt, cg;
    if (bid < 64) { layer = 0; tt = t;     if (tt >= T_STEPS) return; cg = bid; }
    else          { layer = 1; tt = t - 1; if (tt < 0) return;       cg = bid - 64; }

    const unsigned short* hin;
    unsigned short* yout;
    float* cs;
    if (layer == 0) { hin = y0bf + (long)tt * BH; yout = y0bf + (long)(tt + 1) * BH; cs = c0s; }
    else            { hin = y1bf + (long)tt * BH; yout = y1bf + (long)(tt + 1) * BH; cs = c1s; }

    const int n_base = cg * 32;

    // early prefetch of pointwise operands
    const int pb = tid >> 3, pu = tid & 7;
    const int si = pb * HDIM + cg * 8 + pu;
    float creg = 0.0f;
    float4 ad = make_float4(0.f, 0.f, 0.f, 0.f);
    if (tid < 256) {
        creg = cs[si];
        if (layer == 0) ad = *(const float4*)(G0 + ((long)tt * BATCH + pb) * GDIM + n_base + pu * 4);
        else            ad = *(const float4*)(b1p + n_base + pu * 4);
    }

    f32x4 acc[2][2];
    acc[0][0] = (f32x4)0.0f; acc[0][1] = (f32x4)0.0f;
    acc[1][0] = (f32x4)0.0f; acc[1][1] = (f32x4)0.0f;

    if (layer == 0) {
        const int kbase = wv * 64;
        const unsigned short* A0 = hin + fr * 512 + kbase + fq * 8;
        const unsigned short* A1 = A0 + 16 * 512;
        const unsigned short* B0 = Whh0p + (long)(n_base + fr) * 512 + kbase + fq * 8;
        const unsigned short* B1 = B0 + 16 * 512;
        #pragma unroll
        for (int i = 0; i < 2; ++i) {
            bf16x8 a0 = *(const bf16x8*)(A0 + i * 32);
            bf16x8 a1 = *(const bf16x8*)(A1 + i * 32);
            bf16x8 b0 = *(const bf16x8*)(B0 + i * 32);
            bf16x8 b1 = *(const bf16x8*)(B1 + i * 32);
            acc[0][0] = MFMA16(a0, b0, acc[0][0]);
            acc[0][1] = MFMA16(a0, b1, acc[0][1]);
            acc[1][0] = MFMA16(a1, b0, acc[1][0]);
            acc[1][1] = MFMA16(a1, b1, acc[1][1]);
        }
    } else {
        const unsigned short* Aop = (wv < 4) ? (y0bf + (long)(tt + 1) * BH) : hin;
        const unsigned short* Bop = (wv < 4) ? Wih1p : Whh1p;
        const int kbase = (wv & 3) * 128;
        const unsigned short* A0 = Aop + fr * 512 + kbase + fq * 8;
        const unsigned short* A1 = A0 + 16 * 512;
        const unsigned short* B0 = Bop + (long)(n_base + fr) * 512 + kbase + fq * 8;
        const unsigned short* B1 = B0 + 16 * 512;
        #pragma unroll
        for (int i = 0; i < 4; ++i) {
            bf16x8 a0 = *(const bf16x8*)(A0 + i * 32);
            bf16x8 a1 = *(const bf16x8*)(A1 + i * 32);
            bf16x8 b0 = *(const bf16x8*)(B0 + i * 32);
            bf16x8 b1 = *(const bf16x8*)(B1 + i * 32);
            acc[0][0] = MFMA16(a0, b0, acc[0][0]);
            acc[0][1] = MFMA16(a0, b1, acc[0][1]);
            acc[1][0] = MFMA16(a1, b0, acc[1][0]);
            acc[1][1] = MFMA16(a1, b1, acc[1][1]);
        }
    }

    #pragma unroll
    for (int mi = 0; mi < 2; ++mi)
        #pragma unroll
        for (int ni = 0; ni < 2; ++ni)
            #pragma unroll
            for (int r = 0; r < 4; ++r)
                part[wv][mi * 16 + fq * 4 + r][ni * 16 + fr] = acc[mi][ni][r];
    __syncthreads();

    if (tid < 256) {
        float4 g4 = *(const float4*)&part[0][pb][pu * 4];
        #pragma unroll
        for (int w = 1; w < 8; ++w) {
            float4 p4 = *(const float4*)&part[w][pb][pu * 4];
            g4.x += p4.x; g4.y += p4.y; g4.z += p4.z; g4.w += p4.w;
        }
        const float vi = g4.x + ad.x, vf = g4.y + ad.y;
        const float vg = g4.z + ad.z, vo = g4.w + ad.w;
        float c = fsigmoid(vf) * creg + fsigmoid(vi) * ftanh(vg);
        float h = fsigmoid(vo) * ftanh(c);
        cs[si] = c;
        yout[si] = f2bf(h);
        if (tt == T_STEPS - 1) hf[layer * BH + si] = h;
    }
}

// remaining decode tiles (last m-groups, ready only after the recurrence)
__global__ __launch_bounds__(512) void decode_tail(const unsigned short* __restrict__ y1bf,
                                                   const unsigned short* __restrict__ decWb,
                                                   const float* __restrict__ dec_b,
                                                   float* __restrict__ out, int tau0) {
    __shared__ __align__(16) char smem[32768];
    decode_tile(tau0 + blockIdx.x, y1bf + BH, decWb, dec_b, out, smem, threadIdx.x);
}

// d_out tail: [h_f0 | h_f1 | c_f0 | c_f1]
__global__ __launch_bounds__(256) void finalize_states(const float* __restrict__ hf,
                                                       const float* __restrict__ c0s,
                                                       const float* __restrict__ c1s,
                                                       float* __restrict__ out) {
    const int idx = blockIdx.x * 256 + threadIdx.x;
    const long base = (long)MROWS * VOCAB;
    float v;
    if (idx < 32768)      v = hf[idx];
    else if (idx < 49152) v = c0s[idx - 32768];
    else                  v = c1s[idx - 49152];
    out[base + idx] = v;
}

// ---------------------------------------------------------------------------
extern "C" void kernel_launch(void* const* d_in, const int* in_sizes, int n_in,
                              void* d_out, int out_size, void* d_ws, size_t ws_size,
                              hipStream_t stream) {
    const int*   word  = (const int*)d_in[0];
    const int*   seq   = (const int*)d_in[1];
    const float* emb   = (const float*)d_in[2];
    const float* w2hW  = (const float*)d_in[3];
    const float* w2hb  = (const float*)d_in[4];
    const float* Wih0  = (const float*)d_in[5];
    const float* Whh0  = (const float*)d_in[6];
    const float* bih0  = (const float*)d_in[7];
    const float* bhh0  = (const float*)d_in[8];
    const float* Wih1  = (const float*)d_in[9];
    const float* Whh1  = (const float*)d_in[10];
    const float* bih1  = (const float*)d_in[11];
    const float* bhh1  = (const float*)d_in[12];
    const float* dec_W = (const float*)d_in[13];
    const float* dec_b = (const float*)d_in[14];
    float* out = (float*)d_out;

    char* ws = (char*)d_ws;
    size_t off = 0;
    float*          G0    = (float*)(ws + off);          off += (size_t)MROWS * GDIM * 4;
    unsigned short* Xbf   = (unsigned short*)(ws + off); off += (size_t)MROWS * EDIM * 2;
    unsigned short* Wih0p = (unsigned short*)(ws + off); off += (size_t)GDIM  * EDIM * 2;
    unsigned short* Whh0p = (unsigned short*)(ws + off); off += (size_t)GDIM  * HDIM * 2;
    unsigned short* Wih1p = (unsigned short*)(ws + off); off += (size_t)GDIM  * HDIM * 2;
    unsigned short* Whh1p = (unsigned short*)(ws + off); off += (size_t)GDIM  * HDIM * 2;
    unsigned short* decWb = (unsigned short*)(ws + off); off += (size_t)VPAD  * EDIM * 2;
    unsigned short* y0bf  = (unsigned short*)(ws + off); off += (size_t)(T_STEPS + 1) * BH * 2;
    unsigned short* y1bf  = (unsigned short*)(ws + off); off += (size_t)(T_STEPS + 1) * BH * 2;
    float* b0p = (float*)(ws + off); off += (size_t)GDIM * 4;
    float* b1p = (float*)(ws + off); off += (size_t)GDIM * 4;
    float* c0s = (float*)(ws + off); off += (size_t)BH * 4;
    float* c1s = (float*)(ws + off); off += (size_t)BH * 4;
    float* hf  = (float*)(ws + off); off += (size_t)2 * BH * 4;
    // total ~106 MB of d_ws

    // prologue
    pack_all<<<4 * 2048, 64, 0, stream>>>(Wih0, Whh0, Wih1, Whh1,
                                          Wih0p, Whh0p, Wih1p, Whh1p);
    pack_bias<<<8, 256, 0, stream>>>(bih0, bhh0, bih1, bhh1, b0p, b1p);
    gather_x<<<2048, 256, 0, stream>>>(seq, emb, Xbf);
    init_c0<<<64, 256, 0, stream>>>(word, emb, w2hW, w2hb, c0s, c1s, y0bf, y1bf);

    // G0 = X @ Wih0p^T + b0p  [4096x2048], K=512; + dec_W conversion blocks
    gemm_bt128<<<512 + 12512, 256, 0, stream>>>(Xbf, Wih0p, G0, b0p,
                                                512, GDIM, (long)GDIM, 16,
                                                dec_W, decWb, 512);

    // readiness-safe decode tile schedule: S(d) cumulative tiles by dispatch d
    auto S = [](int d) -> int {
        if (d <= 6) return 0;
        long v = (long)NTILE_N * (d - 6) / 4;
        return (v > FUSED_TILES) ? FUSED_TILES : (int)v;
    };

    // skewed recurrence + streamed decode tiles on idle CUs
    for (int t = 0; t <= T_STEPS; ++t) {
        const int sd = S(t), ntiles = S(t + 1) - sd;
        lstm_step2<<<128 + ntiles, 512, 0, stream>>>(
            G0, Whh0p, Wih1p, Whh1p, b1p, y0bf, y1bf, c0s, c1s, hf,
            decWb, dec_b, out, t, sd);
    }

    // decode tiles not coverable during the recurrence (last m-groups)
    decode_tail<<<NTILES_TOT - FUSED_TILES, 512, 0, stream>>>(y1bf, decWb, dec_b,
                                                              out, FUSED_TILES);

    finalize_states<<<256, 256, 0, stream>>>(hf, c0s, c1s, out);
}

// Round 11
// 1364.145 us; speedup vs baseline: 1.4326x; 1.4326x over previous
//
#include <hip/hip_runtime.h>
#include <hip/hip_bf16.h>
#include <cstdint>

// Problem dims
#define T_STEPS 128
#define BATCH   32
#define VOCAB   50000
#define EDIM    512
#define HDIM    512
#define GDIM    2048          // 4*H
#define MROWS   4096          // T*B
#define VPAD    50048         // padded rows of decWb
#define BH      (BATCH * HDIM)

typedef short bf16x8 __attribute__((ext_vector_type(8)));
typedef float f32x4  __attribute__((ext_vector_type(4)));
typedef unsigned short us4 __attribute__((ext_vector_type(4)));
typedef unsigned short us8 __attribute__((ext_vector_type(8)));

#define MFMA16(a, b, c) __builtin_amdgcn_mfma_f32_16x16x32_bf16(a, b, c, 0, 0, 0)

__device__ __forceinline__ float fsigmoid(float x) { return 1.0f / (1.0f + __expf(-x)); }
__device__ __forceinline__ float ftanh(float x)    { return 1.0f - 2.0f / (1.0f + __expf(2.0f * x)); }

// round-to-nearest-even fp32 -> bf16 bits
__device__ __forceinline__ unsigned short f2bf(float f) {
    unsigned int u = __float_as_uint(f);
    u = (u + 0x7fffu + ((u >> 16) & 1u)) >> 16;
    return (unsigned short)u;
}

// ---------------------------------------------------------------------------
// Prologue kernels
// ---------------------------------------------------------------------------

// Gate-interleaved pack+convert for all 4 recurrent weight mats in one launch
__global__ __launch_bounds__(64) void pack_all(const float* __restrict__ s0,
                                               const float* __restrict__ s1,
                                               const float* __restrict__ s2,
                                               const float* __restrict__ s3,
                                               unsigned short* __restrict__ d0,
                                               unsigned short* __restrict__ d1,
                                               unsigned short* __restrict__ d2,
                                               unsigned short* __restrict__ d3) {
    const int which = blockIdx.x >> 11;             // 0..3
    const int n = blockIdx.x & 2047;                // packed row
    const float* src = (which == 0) ? s0 : (which == 1) ? s1 : (which == 2) ? s2 : s3;
    unsigned short* dst = (which == 0) ? d0 : (which == 1) ? d1 : (which == 2) ? d2 : d3;
    const int orig = (n & 3) * 512 + (n >> 2);
    const int k = threadIdx.x * 8;
    const float* s = src + (long)orig * 512 + k;
    float4 a = *(const float4*)s;
    float4 b = *(const float4*)(s + 4);
    us8 v;
    v[0] = f2bf(a.x); v[1] = f2bf(a.y); v[2] = f2bf(a.z); v[3] = f2bf(a.w);
    v[4] = f2bf(b.x); v[5] = f2bf(b.y); v[6] = f2bf(b.z); v[7] = f2bf(b.w);
    *(us8*)(dst + (long)n * 512 + k) = v;
}

// packed bias sums
__global__ __launch_bounds__(256) void pack_bias(const float* __restrict__ bih0,
                                                 const float* __restrict__ bhh0,
                                                 const float* __restrict__ bih1,
                                                 const float* __restrict__ bhh1,
                                                 float* __restrict__ b0p,
                                                 float* __restrict__ b1p) {
    const int n = blockIdx.x * 256 + threadIdx.x;   // 0..2047
    const int orig = (n & 3) * 512 + (n >> 2);
    b0p[n] = bih0[orig] + bhh0[orig];
    b1p[n] = bih1[orig] + bhh1[orig];
}

// X[r, :] = bf16(emb[seq[r], :])
__global__ __launch_bounds__(256) void gather_x(const int* __restrict__ seq,
                                                const float* __restrict__ emb,
                                                unsigned short* __restrict__ Xbf) {
    long i = ((long)blockIdx.x * 256 + threadIdx.x) * 4;
    if (i >= (long)MROWS * EDIM) return;
    int r   = (int)(i >> 9);
    int col = (int)(i & 511);
    const float* er = emb + (long)seq[r] * EDIM + col;
    float4 e = *(const float4*)er;
    us4 v;
    v[0] = f2bf(e.x); v[1] = f2bf(e.y); v[2] = f2bf(e.z); v[3] = f2bf(e.w);
    *(us4*)(Xbf + i) = v;
}

// c0 init for both layers; h0 = 0 in slot 0 of y buffers
__global__ __launch_bounds__(256) void init_c0(const int* __restrict__ word,
                                               const float* __restrict__ emb,
                                               const float* __restrict__ w2hW,
                                               const float* __restrict__ w2hb,
                                               float* __restrict__ c0s, float* __restrict__ c1s,
                                               unsigned short* __restrict__ y0bf,
                                               unsigned short* __restrict__ y1bf) {
    const int idx = blockIdx.x * 256 + threadIdx.x;   // 0..16383
    const int b = idx >> 9, hh = idx & 511;
    const float* er = emb + (long)word[b] * EDIM;
    const float* wr = w2hW + (long)hh * EDIM;
    float acc = w2hb[hh];
    #pragma unroll 4
    for (int k = 0; k < EDIM; k += 4) {
        float4 e4 = *(const float4*)(er + k);
        float4 w4 = *(const float4*)(wr + k);
        acc += e4.x * w4.x + e4.y * w4.y + e4.z * w4.z + e4.w * w4.w;
    }
    c0s[idx] = acc;
    c1s[idx] = acc;
    y0bf[idx] = 0;
    y1bf[idx] = 0;
}

// ---------------------------------------------------------------------------
// MFMA GEMM: C[m,n] = sum_k A[m,k]*Bt[n,k] + bias1[n]. n-fastest block order
// (R1/R6-measured best). Double-buffered K-loop with counted vmcnt(8): tile
// k+1's global_load_lds issue overlaps tile k's MFMA (T4). LDS-staged
// epilogue -> 512B-contiguous stores per wave. Blocks >= ngemm carry dec_W
// fp32->bf16 conversion slices (independent prologue work on idle CUs).
// Double-buffer base derived via runtime offset arithmetic (NO arrays of LDS
// pointers: addrspacecast static initializers don't compile on gfx950).
// ---------------------------------------------------------------------------
__global__ __launch_bounds__(256) void gemm_bt128(const unsigned short* __restrict__ A,
                                                  const unsigned short* __restrict__ Bt,
                                                  float* __restrict__ C,
                                                  const float* __restrict__ bias1,
                                                  int K, int Nreal, long ldc, int ntn,
                                                  const float* __restrict__ cvsrc,
                                                  unsigned short* __restrict__ cvdst,
                                                  int ngemm) {
    const int tid  = threadIdx.x;
    if (blockIdx.x >= ngemm) {
        // dec_W conversion slice: 2048 elems/block
        long i = ((long)(blockIdx.x - ngemm) * 256 + tid) * 8;
        if (i >= (long)VPAD * EDIM) return;
        long row = i >> 9;
        us8 v;
        if (row < VOCAB) {
            float4 a = *(const float4*)(cvsrc + i);
            float4 b = *(const float4*)(cvsrc + i + 4);
            v[0] = f2bf(a.x); v[1] = f2bf(a.y); v[2] = f2bf(a.z); v[3] = f2bf(a.w);
            v[4] = f2bf(b.x); v[5] = f2bf(b.y); v[6] = f2bf(b.z); v[7] = f2bf(b.w);
        } else {
            v = (us8)0;
        }
        *(us8*)(cvdst + i) = v;
        return;
    }

    __shared__ __align__(16) unsigned char smem[65536];   // 2x(As|Bs) dbuf / ctile
    float* ctile = (float*)smem;                          // [64][132] (33.8KB)

    const long m0  = (long)(blockIdx.x / ntn) * 128;
    const long n0  = (long)(blockIdx.x % ntn) * 128;
    const int lane = tid & 63;
    const int wave = tid >> 6;
    const int wr = wave >> 1, wc = wave & 1;
    const int fr = lane & 15, fq = lane >> 4;
    const int srow = tid >> 3;
    const int scol = (tid & 7) * 8;

    f32x4 acc[4][4];
    #pragma unroll
    for (int i = 0; i < 4; ++i)
        #pragma unroll
        for (int j = 0; j < 4; ++j) acc[i][j] = (f32x4)0.0f;

    // issue one K-tile's 8 async loads into buffer b (LDS base by offset calc)
    auto issue = [&](int kt, int b) {
        unsigned short* As = (unsigned short*)(smem + (b << 15));
        unsigned short* Bs = (unsigned short*)(smem + (b << 15) + 16384);
        #pragma unroll
        for (int i = 0; i < 4; ++i) {
            const unsigned short* ga = A  + (m0 + i * 32 + srow) * K + kt + scol;
            const unsigned short* gb = Bt + (n0 + i * 32 + srow) * K + kt + scol;
            __builtin_amdgcn_global_load_lds((const __attribute__((address_space(1))) void*)ga,
                                             (__attribute__((address_space(3))) void*)(As + i * 2048 + tid * 8),
                                             16, 0, 0);
            __builtin_amdgcn_global_load_lds((const __attribute__((address_space(1))) void*)gb,
                                             (__attribute__((address_space(3))) void*)(Bs + i * 2048 + tid * 8),
                                             16, 0, 0);
        }
    };

    const int NK = K >> 6;
    issue(0, 0);
    for (int k = 0; k < NK; ++k) {
        const int cur = k & 1;
        if (k + 1 < NK) {
            issue((k + 1) << 6, cur ^ 1);
            asm volatile("s_waitcnt vmcnt(8)" ::: "memory");   // tile k's 8 oldest done
        } else {
            asm volatile("s_waitcnt vmcnt(0)" ::: "memory");
        }
        __syncthreads();                                       // buf[cur] published
        const unsigned short* Asc = (const unsigned short*)(smem + (cur << 15));
        const unsigned short* Bsc = (const unsigned short*)(smem + (cur << 15) + 16384);
        #pragma unroll
        for (int ks = 0; ks < 64; ks += 32) {
            bf16x8 af[4], bfr[4];
            #pragma unroll
            for (int mi = 0; mi < 4; ++mi)
                af[mi] = *(const bf16x8*)&Asc[(wr * 64 + mi * 16 + fr) * 64 + ks + fq * 8];
            #pragma unroll
            for (int ni = 0; ni < 4; ++ni)
                bfr[ni] = *(const bf16x8*)&Bsc[(wc * 64 + ni * 16 + fr) * 64 + ks + fq * 8];
            #pragma unroll
            for (int mi = 0; mi < 4; ++mi)
                #pragma unroll
                for (int ni = 0; ni < 4; ++ni)
                    acc[mi][ni] = MFMA16(af[mi], bfr[ni], acc[mi][ni]);
        }
        __syncthreads();                                       // buf[cur] reusable at k+2
    }

    // staged epilogue: two 64-row halves through LDS, 512B-contiguous stores
    #pragma unroll
    for (int h = 0; h < 2; ++h) {
        if (wr == h) {
            #pragma unroll
            for (int ni = 0; ni < 4; ++ni) {
                const long col = n0 + wc * 64 + ni * 16 + fr;
                float bs = (col < Nreal && bias1) ? bias1[col] : 0.0f;
                #pragma unroll
                for (int mi = 0; mi < 4; ++mi)
                    #pragma unroll
                    for (int r = 0; r < 4; ++r)
                        ctile[(mi * 16 + fq * 4 + r) * 132 + wc * 64 + ni * 16 + fr] =
                            acc[mi][ni][r] + bs;
            }
        }
        __syncthreads();
        #pragma unroll
        for (int j = 0; j < 8; ++j) {
            const int flat = tid + j * 256;          // 0..2047 float4 units
            const int row = flat >> 5, colq = flat & 31;
            const long col4 = n0 + colq * 4;
            if (col4 < Nreal) {                      // Nreal % 4 == 0
                f32x4 v = *(const f32x4*)&ctile[row * 132 + colq * 4];
                *(f32x4*)&C[(m0 + h * 64 + row) * ldc + col4] = v;
            }
        }
        __syncthreads();
    }
}

// ---------------------------------------------------------------------------
// LSTM step, wave-level K-split (skewed): blocks 0..63 layer0 step t (32 packed
// cols each, 8 waves x K=64), blocks 64..127 layer1 step t-1 (32 cols, waves
// 0-3: y0@Wih1^T K=128 chunks, waves 4-7: h@Whh1^T K=128 chunks).
// h-state lives IN y0bf/y1bf (slot s holds h(s-1); slot 0 = zeros).
// G0/bias/c prefetched into registers at entry. Kernel-launch boundary IS the
// cross-block barrier (R3: agent-scope flag sync ~39us/step vs ~6.2us here).
// NO fused extra work: R8 proved any co-scheduled block slower than the ~6.2us
// critical path stretches every dispatch (dispatch ends with slowest block).
// ---------------------------------------------------------------------------
__global__ __launch_bounds__(512) void lstm_step2(
        const float* __restrict__ G0,
        const unsigned short* __restrict__ Whh0p,
        const unsigned short* __restrict__ Wih1p,
        const unsigned short* __restrict__ Whh1p,
        const float* __restrict__ b1p,
        unsigned short* __restrict__ y0bf,         // [T+1][32][512] (slot0 = h init)
        unsigned short* __restrict__ y1bf,
        float* __restrict__ c0s, float* __restrict__ c1s,
        float* __restrict__ hf,
        int t) {
    __shared__ float part[8][32][32];              // 32 KB partial tiles
    int bid = blockIdx.x;
    const int tid  = threadIdx.x;
    const int wv   = tid >> 6, lane = tid & 63;
    const int fr   = lane & 15, fq = lane >> 4;

    int layer, tt, cg;
    if (bid < 64) { layer = 0; tt = t;     if (tt >= T_STEPS) return; cg = bid; }
    else          { layer = 1; tt = t - 1; if (tt < 0) return;       cg = bid - 64; }

    const unsigned short* hin;
    unsigned short* yout;
    float* cs;
    if (layer == 0) { hin = y0bf + (long)tt * BH; yout = y0bf + (long)(tt + 1) * BH; cs = c0s; }
    else            { hin = y1bf + (long)tt * BH; yout = y1bf + (long)(tt + 1) * BH; cs = c1s; }

    const int n_base = cg * 32;

    // early prefetch of pointwise operands (hide latency under MFMA)
    const int pb = tid >> 3, pu = tid & 7;
    const int si = pb * HDIM + cg * 8 + pu;
    float creg = 0.0f;
    float4 ad = make_float4(0.f, 0.f, 0.f, 0.f);
    if (tid < 256) {
        creg = cs[si];
        if (layer == 0) ad = *(const float4*)(G0 + ((long)tt * BATCH + pb) * GDIM + n_base + pu * 4);
        else            ad = *(const float4*)(b1p + n_base + pu * 4);
    }

    f32x4 acc[2][2];
    acc[0][0] = (f32x4)0.0f; acc[0][1] = (f32x4)0.0f;
    acc[1][0] = (f32x4)0.0f; acc[1][1] = (f32x4)0.0f;

    if (layer == 0) {
        const int kbase = wv * 64;
        const unsigned short* A0 = hin + fr * 512 + kbase + fq * 8;
        const unsigned short* A1 = A0 + 16 * 512;
        const unsigned short* B0 = Whh0p + (long)(n_base + fr) * 512 + kbase + fq * 8;
        const unsigned short* B1 = B0 + 16 * 512;
        #pragma unroll
        for (int i = 0; i < 2; ++i) {
            bf16x8 a0 = *(const bf16x8*)(A0 + i * 32);
            bf16x8 a1 = *(const bf16x8*)(A1 + i * 32);
            bf16x8 b0 = *(const bf16x8*)(B0 + i * 32);
            bf16x8 b1 = *(const bf16x8*)(B1 + i * 32);
            acc[0][0] = MFMA16(a0, b0, acc[0][0]);
            acc[0][1] = MFMA16(a0, b1, acc[0][1]);
            acc[1][0] = MFMA16(a1, b0, acc[1][0]);
            acc[1][1] = MFMA16(a1, b1, acc[1][1]);
        }
    } else {
        const unsigned short* Aop = (wv < 4) ? (y0bf + (long)(tt + 1) * BH) : hin;
        const unsigned short* Bop = (wv < 4) ? Wih1p : Whh1p;
        const int kbase = (wv & 3) * 128;
        const unsigned short* A0 = Aop + fr * 512 + kbase + fq * 8;
        const unsigned short* A1 = A0 + 16 * 512;
        const unsigned short* B0 = Bop + (long)(n_base + fr) * 512 + kbase + fq * 8;
        const unsigned short* B1 = B0 + 16 * 512;
        #pragma unroll
        for (int i = 0; i < 4; ++i) {
            bf16x8 a0 = *(const bf16x8*)(A0 + i * 32);
            bf16x8 a1 = *(const bf16x8*)(A1 + i * 32);
            bf16x8 b0 = *(const bf16x8*)(B0 + i * 32);
            bf16x8 b1 = *(const bf16x8*)(B1 + i * 32);
            acc[0][0] = MFMA16(a0, b0, acc[0][0]);
            acc[0][1] = MFMA16(a0, b1, acc[0][1]);
            acc[1][0] = MFMA16(a1, b0, acc[1][0]);
            acc[1][1] = MFMA16(a1, b1, acc[1][1]);
        }
    }

    #pragma unroll
    for (int mi = 0; mi < 2; ++mi)
        #pragma unroll
        for (int ni = 0; ni < 2; ++ni)
            #pragma unroll
            for (int r = 0; r < 4; ++r)
                part[wv][mi * 16 + fq * 4 + r][ni * 16 + fr] = acc[mi][ni][r];
    __syncthreads();

    if (tid < 256) {
        float4 g4 = *(const float4*)&part[0][pb][pu * 4];
        #pragma unroll
        for (int w = 1; w < 8; ++w) {
            float4 p4 = *(const float4*)&part[w][pb][pu * 4];
            g4.x += p4.x; g4.y += p4.y; g4.z += p4.z; g4.w += p4.w;
        }
        const float vi = g4.x + ad.x, vf = g4.y + ad.y;
        const float vg = g4.z + ad.z, vo = g4.w + ad.w;
        float c = fsigmoid(vf) * creg + fsigmoid(vi) * ftanh(vg);
        float h = fsigmoid(vo) * ftanh(c);
        cs[si] = c;
        yout[si] = f2bf(h);
        if (tt == T_STEPS - 1) hf[layer * BH + si] = h;
    }
}

// d_out tail: [h_f0 | h_f1 | c_f0 | c_f1]
__global__ __launch_bounds__(256) void finalize_states(const float* __restrict__ hf,
                                                       const float* __restrict__ c0s,
                                                       const float* __restrict__ c1s,
                                                       float* __restrict__ out) {
    const int idx = blockIdx.x * 256 + threadIdx.x;
    const long base = (long)MROWS * VOCAB;
    float v;
    if (idx < 32768)      v = hf[idx];
    else if (idx < 49152) v = c0s[idx - 32768];
    else                  v = c1s[idx - 49152];
    out[base + idx] = v;
}

// ---------------------------------------------------------------------------
extern "C" void kernel_launch(void* const* d_in, const int* in_sizes, int n_in,
                              void* d_out, int out_size, void* d_ws, size_t ws_size,
                              hipStream_t stream) {
    const int*   word  = (const int*)d_in[0];
    const int*   seq   = (const int*)d_in[1];
    const float* emb   = (const float*)d_in[2];
    const float* w2hW  = (const float*)d_in[3];
    const float* w2hb  = (const float*)d_in[4];
    const float* Wih0  = (const float*)d_in[5];
    const float* Whh0  = (const float*)d_in[6];
    const float* bih0  = (const float*)d_in[7];
    const float* bhh0  = (const float*)d_in[8];
    const float* Wih1  = (const float*)d_in[9];
    const float* Whh1  = (const float*)d_in[10];
    const float* bih1  = (const float*)d_in[11];
    const float* bhh1  = (const float*)d_in[12];
    const float* dec_W = (const float*)d_in[13];
    const float* dec_b = (const float*)d_in[14];
    float* out = (float*)d_out;

    char* ws = (char*)d_ws;
    size_t off = 0;
    float*          G0    = (float*)(ws + off);          off += (size_t)MROWS * GDIM * 4;
    unsigned short* Xbf   = (unsigned short*)(ws + off); off += (size_t)MROWS * EDIM * 2;
    unsigned short* Wih0p = (unsigned short*)(ws + off); off += (size_t)GDIM  * EDIM * 2;
    unsigned short* Whh0p = (unsigned short*)(ws + off); off += (size_t)GDIM  * HDIM * 2;
    unsigned short* Wih1p = (unsigned short*)(ws + off); off += (size_t)GDIM  * HDIM * 2;
    unsigned short* Whh1p = (unsigned short*)(ws + off); off += (size_t)GDIM  * HDIM * 2;
    unsigned short* decWb = (unsigned short*)(ws + off); off += (size_t)VPAD  * EDIM * 2;
    unsigned short* y0bf  = (unsigned short*)(ws + off); off += (size_t)(T_STEPS + 1) * BH * 2;
    unsigned short* y1bf  = (unsigned short*)(ws + off); off += (size_t)(T_STEPS + 1) * BH * 2;
    float* b0p = (float*)(ws + off); off += (size_t)GDIM * 4;
    float* b1p = (float*)(ws + off); off += (size_t)GDIM * 4;
    float* c0s = (float*)(ws + off); off += (size_t)BH * 4;
    float* c1s = (float*)(ws + off); off += (size_t)BH * 4;
    float* hf  = (float*)(ws + off); off += (size_t)2 * BH * 4;
    // total ~106 MB of d_ws

    // prologue
    pack_all<<<4 * 2048, 64, 0, stream>>>(Wih0, Whh0, Wih1, Whh1,
                                          Wih0p, Whh0p, Wih1p, Whh1p);
    pack_bias<<<8, 256, 0, stream>>>(bih0, bhh0, bih1, bhh1, b0p, b1p);
    gather_x<<<2048, 256, 0, stream>>>(seq, emb, Xbf);
    init_c0<<<64, 256, 0, stream>>>(word, emb, w2hW, w2hb, c0s, c1s, y0bf, y1bf);

    // G0 = X @ Wih0p^T + b0p  [4096x2048], K=512; + dec_W conversion blocks
    gemm_bt128<<<512 + 12512, 256, 0, stream>>>(Xbf, Wih0p, G0, b0p,
                                                512, GDIM, (long)GDIM, 16,
                                                dec_W, decWb, 512);

    // skewed recurrence: layer0 step t || layer1 step t-1
    for (int t = 0; t <= T_STEPS; ++t)
        lstm_step2<<<128, 512, 0, stream>>>(G0, Whh0p, Wih1p, Whh1p, b1p,
                                            y0bf, y1bf, c0s, c1s, hf, t);

    // decoded = y1 @ dec_W^T + dec_b   [4096 x 50000], K=512
    gemm_bt128<<<32 * 391, 256, 0, stream>>>(y1bf + BH, decWb, out, dec_b,
                                             512, VOCAB, (long)VOCAB, 391,
                                             nullptr, nullptr, 32 * 391);

    finalize_states<<<256, 256, 0, stream>>>(hf, c0s, c1s, out);
}

// Round 12
// 1259.007 us; speedup vs baseline: 1.5523x; 1.0835x over previous
//
#include <hip/hip_runtime.h>
#include <hip/hip_bf16.h>
#include <cstdint>

// Problem dims
#define T_STEPS 128
#define BATCH   32
#define VOCAB   50000
#define EDIM    512
#define HDIM    512
#define GDIM    2048          // 4*H
#define MROWS   4096          // T*B
#define VPAD    50048         // padded rows of decWb
#define BH      (BATCH * HDIM)

typedef short bf16x8 __attribute__((ext_vector_type(8)));
typedef float f32x4  __attribute__((ext_vector_type(4)));
typedef unsigned short us4 __attribute__((ext_vector_type(4)));
typedef unsigned short us8 __attribute__((ext_vector_type(8)));

#define MFMA16(a, b, c) __builtin_amdgcn_mfma_f32_16x16x32_bf16(a, b, c, 0, 0, 0)

__device__ __forceinline__ float fsigmoid(float x) { return 1.0f / (1.0f + __expf(-x)); }
__device__ __forceinline__ float ftanh(float x)    { return 1.0f - 2.0f / (1.0f + __expf(2.0f * x)); }

// round-to-nearest-even fp32 -> bf16 bits
__device__ __forceinline__ unsigned short f2bf(float f) {
    unsigned int u = __float_as_uint(f);
    u = (u + 0x7fffu + ((u >> 16) & 1u)) >> 16;
    return (unsigned short)u;
}

// ---------------------------------------------------------------------------
// Prologue kernels
// ---------------------------------------------------------------------------

// Gate-interleaved pack+convert for all 4 recurrent weight mats in one launch
__global__ __launch_bounds__(64) void pack_all(const float* __restrict__ s0,
                                               const float* __restrict__ s1,
                                               const float* __restrict__ s2,
                                               const float* __restrict__ s3,
                                               unsigned short* __restrict__ d0,
                                               unsigned short* __restrict__ d1,
                                               unsigned short* __restrict__ d2,
                                               unsigned short* __restrict__ d3) {
    const int which = blockIdx.x >> 11;             // 0..3
    const int n = blockIdx.x & 2047;                // packed row
    const float* src = (which == 0) ? s0 : (which == 1) ? s1 : (which == 2) ? s2 : s3;
    unsigned short* dst = (which == 0) ? d0 : (which == 1) ? d1 : (which == 2) ? d2 : d3;
    const int orig = (n & 3) * 512 + (n >> 2);
    const int k = threadIdx.x * 8;
    const float* s = src + (long)orig * 512 + k;
    float4 a = *(const float4*)s;
    float4 b = *(const float4*)(s + 4);
    us8 v;
    v[0] = f2bf(a.x); v[1] = f2bf(a.y); v[2] = f2bf(a.z); v[3] = f2bf(a.w);
    v[4] = f2bf(b.x); v[5] = f2bf(b.y); v[6] = f2bf(b.z); v[7] = f2bf(b.w);
    *(us8*)(dst + (long)n * 512 + k) = v;
}

// packed bias sums
__global__ __launch_bounds__(256) void pack_bias(const float* __restrict__ bih0,
                                                 const float* __restrict__ bhh0,
                                                 const float* __restrict__ bih1,
                                                 const float* __restrict__ bhh1,
                                                 float* __restrict__ b0p,
                                                 float* __restrict__ b1p) {
    const int n = blockIdx.x * 256 + threadIdx.x;   // 0..2047
    const int orig = (n & 3) * 512 + (n >> 2);
    b0p[n] = bih0[orig] + bhh0[orig];
    b1p[n] = bih1[orig] + bhh1[orig];
}

// X[r, :] = bf16(emb[seq[r], :])
__global__ __launch_bounds__(256) void gather_x(const int* __restrict__ seq,
                                                const float* __restrict__ emb,
                                                unsigned short* __restrict__ Xbf) {
    long i = ((long)blockIdx.x * 256 + threadIdx.x) * 4;
    if (i >= (long)MROWS * EDIM) return;
    int r   = (int)(i >> 9);
    int col = (int)(i & 511);
    const float* er = emb + (long)seq[r] * EDIM + col;
    float4 e = *(const float4*)er;
    us4 v;
    v[0] = f2bf(e.x); v[1] = f2bf(e.y); v[2] = f2bf(e.z); v[3] = f2bf(e.w);
    *(us4*)(Xbf + i) = v;
}

// c0 init for both layers; h0 = 0 in slot 0 of y buffers
__global__ __launch_bounds__(256) void init_c0(const int* __restrict__ word,
                                               const float* __restrict__ emb,
                                               const float* __restrict__ w2hW,
                                               const float* __restrict__ w2hb,
                                               float* __restrict__ c0s, float* __restrict__ c1s,
                                               unsigned short* __restrict__ y0bf,
                                               unsigned short* __restrict__ y1bf) {
    const int idx = blockIdx.x * 256 + threadIdx.x;   // 0..16383
    const int b = idx >> 9, hh = idx & 511;
    const float* er = emb + (long)word[b] * EDIM;
    const float* wr = w2hW + (long)hh * EDIM;
    float acc = w2hb[hh];
    #pragma unroll 4
    for (int k = 0; k < EDIM; k += 4) {
        float4 e4 = *(const float4*)(er + k);
        float4 w4 = *(const float4*)(wr + k);
        acc += e4.x * w4.x + e4.y * w4.y + e4.z * w4.z + e4.w * w4.w;
    }
    c0s[idx] = acc;
    c1s[idx] = acc;
    y0bf[idx] = 0;
    y1bf[idx] = 0;
}

// ---------------------------------------------------------------------------
// MFMA GEMM, 256(M)x128(N) tile, BK=64, 512 threads = 8 waves (4m x 2n), each
// wave a 64x64 sub-tile via 4x4 fragments of 16x16x32 (same per-wave unit as
// the proven 128^2 kernel). Bigger M-tile halves B re-streaming (decode FETCH).
// n-fastest block order; single-buffered staging (dbuf measured neutral, R10);
// LDS-staged epilogue -> 512B-contiguous stores. Blocks >= ngemm carry dec_W
// fp32->bf16 conversion slices (independent prologue work on idle CUs).
// ---------------------------------------------------------------------------
__global__ __launch_bounds__(512, 4) void gemm_bt256(const unsigned short* __restrict__ A,
                                                     const unsigned short* __restrict__ Bt,
                                                     float* __restrict__ C,
                                                     const float* __restrict__ bias1,
                                                     int K, int Nreal, long ldc, int ntn,
                                                     const float* __restrict__ cvsrc,
                                                     unsigned short* __restrict__ cvdst,
                                                     int ngemm) {
    const int tid = threadIdx.x;
    if (blockIdx.x >= ngemm) {
        // dec_W conversion slice: 4096 elems/block (512 threads x 8)
        long i = ((long)(blockIdx.x - ngemm) * 512 + tid) * 8;
        if (i >= (long)VPAD * EDIM) return;
        long row = i >> 9;
        us8 v;
        if (row < VOCAB) {
            float4 a = *(const float4*)(cvsrc + i);
            float4 b = *(const float4*)(cvsrc + i + 4);
            v[0] = f2bf(a.x); v[1] = f2bf(a.y); v[2] = f2bf(a.z); v[3] = f2bf(a.w);
            v[4] = f2bf(b.x); v[5] = f2bf(b.y); v[6] = f2bf(b.z); v[7] = f2bf(b.w);
        } else {
            v = (us8)0;
        }
        *(us8*)(cvdst + i) = v;
        return;
    }

    __shared__ __align__(16) unsigned char smem[49152];   // As 32KB | Bs 16KB; ctile aliases
    unsigned short* As = (unsigned short*)smem;           // [256][64]
    unsigned short* Bs = (unsigned short*)(smem + 32768); // [128][64]
    float* ctile = (float*)smem;                          // [64][132] (33.8KB)

    const long m0  = (long)(blockIdx.x / ntn) * 256;
    const long n0  = (long)(blockIdx.x % ntn) * 128;
    const int lane = tid & 63;
    const int wave = tid >> 6;
    const int wr = wave >> 1, wc = wave & 1;              // 4m x 2n wave grid
    const int fr = lane & 15, fq = lane >> 4;
    const int srow = tid >> 3;                            // 0..63
    const int scol = (tid & 7) * 8;

    f32x4 acc[4][4];
    #pragma unroll
    for (int i = 0; i < 4; ++i)
        #pragma unroll
        for (int j = 0; j < 4; ++j) acc[i][j] = (f32x4)0.0f;

    for (int kt = 0; kt < K; kt += 64) {
        #pragma unroll
        for (int i = 0; i < 4; ++i) {
            const unsigned short* ga = A + (m0 + i * 64 + srow) * K + kt + scol;
            __builtin_amdgcn_global_load_lds((const __attribute__((address_space(1))) void*)ga,
                                             (__attribute__((address_space(3))) void*)(As + i * 4096 + tid * 8),
                                             16, 0, 0);
        }
        #pragma unroll
        for (int i = 0; i < 2; ++i) {
            const unsigned short* gb = Bt + (n0 + i * 64 + srow) * K + kt + scol;
            __builtin_amdgcn_global_load_lds((const __attribute__((address_space(1))) void*)gb,
                                             (__attribute__((address_space(3))) void*)(Bs + i * 4096 + tid * 8),
                                             16, 0, 0);
        }
        asm volatile("s_waitcnt vmcnt(0)" ::: "memory");
        __syncthreads();
        #pragma unroll
        for (int ks = 0; ks < 64; ks += 32) {
            bf16x8 af[4], bfr[4];
            #pragma unroll
            for (int mi = 0; mi < 4; ++mi)
                af[mi] = *(const bf16x8*)&As[(wr * 64 + mi * 16 + fr) * 64 + ks + fq * 8];
            #pragma unroll
            for (int ni = 0; ni < 4; ++ni)
                bfr[ni] = *(const bf16x8*)&Bs[(wc * 64 + ni * 16 + fr) * 64 + ks + fq * 8];
            #pragma unroll
            for (int mi = 0; mi < 4; ++mi)
                #pragma unroll
                for (int ni = 0; ni < 4; ++ni)
                    acc[mi][ni] = MFMA16(af[mi], bfr[ni], acc[mi][ni]);
        }
        __syncthreads();
    }

    // staged epilogue: four 64-row quarters through LDS, contiguous stores
    #pragma unroll
    for (int h = 0; h < 4; ++h) {
        if (wr == h) {
            #pragma unroll
            for (int ni = 0; ni < 4; ++ni) {
                const long col = n0 + wc * 64 + ni * 16 + fr;
                float bs = (col < Nreal && bias1) ? bias1[col] : 0.0f;
                #pragma unroll
                for (int mi = 0; mi < 4; ++mi)
                    #pragma unroll
                    for (int r = 0; r < 4; ++r)
                        ctile[(mi * 16 + fq * 4 + r) * 132 + wc * 64 + ni * 16 + fr] =
                            acc[mi][ni][r] + bs;
            }
        }
        __syncthreads();
        #pragma unroll
        for (int j = 0; j < 4; ++j) {
            const int flat = tid + j * 512;          // 0..2047 float4 units
            const int row = flat >> 5, colq = flat & 31;
            const long col4 = n0 + colq * 4;
            if (col4 < Nreal) {                      // Nreal % 4 == 0
                f32x4 v = *(const f32x4*)&ctile[row * 132 + colq * 4];
                *(f32x4*)&C[(m0 + h * 64 + row) * ldc + col4] = v;
            }
        }
        __syncthreads();
    }
}

// ---------------------------------------------------------------------------
// LSTM step, wave-level K-split (skewed): blocks 0..63 layer0 step t (32 packed
// cols each, 8 waves x K=64), blocks 64..127 layer1 step t-1 (32 cols, waves
// 0-3: y0@Wih1^T K=128 chunks, waves 4-7: h@Whh1^T K=128 chunks).
// h-state lives IN y0bf/y1bf (slot s holds h(s-1); slot 0 = zeros).
// G0/bias/c prefetched into registers at entry. Kernel-launch boundary IS the
// cross-block barrier (R3: agent-scope flag sync forces per-XCD L2
// writeback/invalidate -> ~39us/step vs ~6.3us here). NO fused extra work:
// R8 proved co-scheduled blocks slower than the ~6.3us critical path stretch
// every dispatch (dispatch ends with its slowest block).
// ---------------------------------------------------------------------------
__global__ __launch_bounds__(512) void lstm_step2(
        const float* __restrict__ G0,
        const unsigned short* __restrict__ Whh0p,
        const unsigned short* __restrict__ Wih1p,
        const unsigned short* __restrict__ Whh1p,
        const float* __restrict__ b1p,
        unsigned short* __restrict__ y0bf,         // [T+1][32][512] (slot0 = h init)
        unsigned short* __restrict__ y1bf,
        float* __restrict__ c0s, float* __restrict__ c1s,
        float* __restrict__ hf,
        int t) {
    __shared__ float part[8][32][32];              // 32 KB partial tiles
    int bid = blockIdx.x;
    const int tid  = threadIdx.x;
    const int wv   = tid >> 6, lane = tid & 63;
    const int fr   = lane & 15, fq = lane >> 4;

    int layer, tt, cg;
    if (bid < 64) { layer = 0; tt = t;     if (tt >= T_STEPS) return; cg = bid; }
    else          { layer = 1; tt = t - 1; if (tt < 0) return;       cg = bid - 64; }

    const unsigned short* hin;
    unsigned short* yout;
    float* cs;
    if (layer == 0) { hin = y0bf + (long)tt * BH; yout = y0bf + (long)(tt + 1) * BH; cs = c0s; }
    else            { hin = y1bf + (long)tt * BH; yout = y1bf + (long)(tt + 1) * BH; cs = c1s; }

    const int n_base = cg * 32;

    // early prefetch of pointwise operands (hide latency under MFMA)
    const int pb = tid >> 3, pu = tid & 7;
    const int si = pb * HDIM + cg * 8 + pu;
    float creg = 0.0f;
    float4 ad = make_float4(0.f, 0.f, 0.f, 0.f);
    if (tid < 256) {
        creg = cs[si];
        if (layer == 0) ad = *(const float4*)(G0 + ((long)tt * BATCH + pb) * GDIM + n_base + pu * 4);
        else            ad = *(const float4*)(b1p + n_base + pu * 4);
    }

    f32x4 acc[2][2];
    acc[0][0] = (f32x4)0.0f; acc[0][1] = (f32x4)0.0f;
    acc[1][0] = (f32x4)0.0f; acc[1][1] = (f32x4)0.0f;

    if (layer == 0) {
        const int kbase = wv * 64;
        const unsigned short* A0 = hin + fr * 512 + kbase + fq * 8;
        const unsigned short* A1 = A0 + 16 * 512;
        const unsigned short* B0 = Whh0p + (long)(n_base + fr) * 512 + kbase + fq * 8;
        const unsigned short* B1 = B0 + 16 * 512;
        #pragma unroll
        for (int i = 0; i < 2; ++i) {
            bf16x8 a0 = *(const bf16x8*)(A0 + i * 32);
            bf16x8 a1 = *(const bf16x8*)(A1 + i * 32);
            bf16x8 b0 = *(const bf16x8*)(B0 + i * 32);
            bf16x8 b1 = *(const bf16x8*)(B1 + i * 32);
            acc[0][0] = MFMA16(a0, b0, acc[0][0]);
            acc[0][1] = MFMA16(a0, b1, acc[0][1]);
            acc[1][0] = MFMA16(a1, b0, acc[1][0]);
            acc[1][1] = MFMA16(a1, b1, acc[1][1]);
        }
    } else {
        const unsigned short* Aop = (wv < 4) ? (y0bf + (long)(tt + 1) * BH) : hin;
        const unsigned short* Bop = (wv < 4) ? Wih1p : Whh1p;
        const int kbase = (wv & 3) * 128;
        const unsigned short* A0 = Aop + fr * 512 + kbase + fq * 8;
        const unsigned short* A1 = A0 + 16 * 512;
        const unsigned short* B0 = Bop + (long)(n_base + fr) * 512 + kbase + fq * 8;
        const unsigned short* B1 = B0 + 16 * 512;
        #pragma unroll
        for (int i = 0; i < 4; ++i) {
            bf16x8 a0 = *(const bf16x8*)(A0 + i * 32);
            bf16x8 a1 = *(const bf16x8*)(A1 + i * 32);
            bf16x8 b0 = *(const bf16x8*)(B0 + i * 32);
            bf16x8 b1 = *(const bf16x8*)(B1 + i * 32);
            acc[0][0] = MFMA16(a0, b0, acc[0][0]);
            acc[0][1] = MFMA16(a0, b1, acc[0][1]);
            acc[1][0] = MFMA16(a1, b0, acc[1][0]);
            acc[1][1] = MFMA16(a1, b1, acc[1][1]);
        }
    }

    #pragma unroll
    for (int mi = 0; mi < 2; ++mi)
        #pragma unroll
        for (int ni = 0; ni < 2; ++ni)
            #pragma unroll
            for (int r = 0; r < 4; ++r)
                part[wv][mi * 16 + fq * 4 + r][ni * 16 + fr] = acc[mi][ni][r];
    __syncthreads();

    if (tid < 256) {
        float4 g4 = *(const float4*)&part[0][pb][pu * 4];
        #pragma unroll
        for (int w = 1; w < 8; ++w) {
            float4 p4 = *(const float4*)&part[w][pb][pu * 4];
            g4.x += p4.x; g4.y += p4.y; g4.z += p4.z; g4.w += p4.w;
        }
        const float vi = g4.x + ad.x, vf = g4.y + ad.y;
        const float vg = g4.z + ad.z, vo = g4.w + ad.w;
        float c = fsigmoid(vf) * creg + fsigmoid(vi) * ftanh(vg);
        float h = fsigmoid(vo) * ftanh(c);
        cs[si] = c;
        yout[si] = f2bf(h);
        if (tt == T_STEPS - 1) hf[layer * BH + si] = h;
    }
}

// d_out tail: [h_f0 | h_f1 | c_f0 | c_f1]
__global__ __launch_bounds__(256) void finalize_states(const float* __restrict__ hf,
                                                       const float* __restrict__ c0s,
                                                       const float* __restrict__ c1s,
                                                       float* __restrict__ out) {
    const int idx = blockIdx.x * 256 + threadIdx.x;
    const long base = (long)MROWS * VOCAB;
    float v;
    if (idx < 32768)      v = hf[idx];
    else if (idx < 49152) v = c0s[idx - 32768];
    else                  v = c1s[idx - 49152];
    out[base + idx] = v;
}

// ---------------------------------------------------------------------------
extern "C" void kernel_launch(void* const* d_in, const int* in_sizes, int n_in,
                              void* d_out, int out_size, void* d_ws, size_t ws_size,
                              hipStream_t stream) {
    const int*   word  = (const int*)d_in[0];
    const int*   seq   = (const int*)d_in[1];
    const float* emb   = (const float*)d_in[2];
    const float* w2hW  = (const float*)d_in[3];
    const float* w2hb  = (const float*)d_in[4];
    const float* Wih0  = (const float*)d_in[5];
    const float* Whh0  = (const float*)d_in[6];
    const float* bih0  = (const float*)d_in[7];
    const float* bhh0  = (const float*)d_in[8];
    const float* Wih1  = (const float*)d_in[9];
    const float* Whh1  = (const float*)d_in[10];
    const float* bih1  = (const float*)d_in[11];
    const float* bhh1  = (const float*)d_in[12];
    const float* dec_W = (const float*)d_in[13];
    const float* dec_b = (const float*)d_in[14];
    float* out = (float*)d_out;

    char* ws = (char*)d_ws;
    size_t off = 0;
    float*          G0    = (float*)(ws + off);          off += (size_t)MROWS * GDIM * 4;
    unsigned short* Xbf   = (unsigned short*)(ws + off); off += (size_t)MROWS * EDIM * 2;
    unsigned short* Wih0p = (unsigned short*)(ws + off); off += (size_t)GDIM  * EDIM * 2;
    unsigned short* Whh0p = (unsigned short*)(ws + off); off += (size_t)GDIM  * HDIM * 2;
    unsigned short* Wih1p = (unsigned short*)(ws + off); off += (size_t)GDIM  * HDIM * 2;
    unsigned short* Whh1p = (unsigned short*)(ws + off); off += (size_t)GDIM  * HDIM * 2;
    unsigned short* decWb = (unsigned short*)(ws + off); off += (size_t)VPAD  * EDIM * 2;
    unsigned short* y0bf  = (unsigned short*)(ws + off); off += (size_t)(T_STEPS + 1) * BH * 2;
    unsigned short* y1bf  = (unsigned short*)(ws + off); off += (size_t)(T_STEPS + 1) * BH * 2;
    float* b0p = (float*)(ws + off); off += (size_t)GDIM * 4;
    float* b1p = (float*)(ws + off); off += (size_t)GDIM * 4;
    float* c0s = (float*)(ws + off); off += (size_t)BH * 4;
    float* c1s = (float*)(ws + off); off += (size_t)BH * 4;
    float* hf  = (float*)(ws + off); off += (size_t)2 * BH * 4;
    // total ~106 MB of d_ws

    // prologue
    pack_all<<<4 * 2048, 64, 0, stream>>>(Wih0, Whh0, Wih1, Whh1,
                                          Wih0p, Whh0p, Wih1p, Whh1p);
    pack_bias<<<8, 256, 0, stream>>>(bih0, bhh0, bih1, bhh1, b0p, b1p);
    gather_x<<<2048, 256, 0, stream>>>(seq, emb, Xbf);
    init_c0<<<64, 256, 0, stream>>>(word, emb, w2hW, w2hb, c0s, c1s, y0bf, y1bf);

    // G0 = X @ Wih0p^T + b0p  [4096x2048], K=512 (16m x 16n tiles of 256x128)
    // + 6256 dec_W conversion blocks on idle CUs
    gemm_bt256<<<256 + 6256, 512, 0, stream>>>(Xbf, Wih0p, G0, b0p,
                                               512, GDIM, (long)GDIM, 16,
                                               dec_W, decWb, 256);

    // skewed recurrence: layer0 step t || layer1 step t-1
    for (int t = 0; t <= T_STEPS; ++t)
        lstm_step2<<<128, 512, 0, stream>>>(G0, Whh0p, Wih1p, Whh1p, b1p,
                                            y0bf, y1bf, c0s, c1s, hf, t);

    // decoded = y1 @ dec_W^T + dec_b   [4096 x 50000], K=512  (16m x 391n tiles)
    gemm_bt256<<<16 * 391, 512, 0, stream>>>(y1bf + BH, decWb, out, dec_b,
                                             512, VOCAB, (long)VOCAB, 391,
                                             nullptr, nullptr, 16 * 391);

    finalize_states<<<256, 256, 0, stream>>>(hf, c0s, c1s, out);
}